// Round 1
// baseline (5509.297 us; speedup 1.0000x reference)
//
#include <hip/hip_runtime.h>

#define LOOKBACK 48
#define HORIZON  12
#define TTOT     60
#define INPUT_DIM 8
#define HIDDEN   128
#define GATES    512   /* 4*HIDDEN */
#define BATCH    8192
#define TILE_B   32
#define NTHREADS 512

/* d_ws float layout */
#define WT0_K    (INPUT_DIM + HIDDEN)          /* 136 */
#define WT0_OFF  0
#define WT1_K    (2 * HIDDEN)                  /* 256 */
#define WT1_OFF  (WT0_K * GATES)               /* 69632 */
#define B0_OFF   (WT1_OFF + WT1_K * GATES)     /* 200704 */
#define B1_OFF   (B0_OFF + GATES)
#define WS_FLOATS (B1_OFF + GATES)             /* 201728 floats ~ 807 KB */

// ---------------- setup: transpose weights to WT[k][g], fuse biases ----------------
__global__ void setup_kernel(const float* __restrict__ W_ih_0,
                             const float* __restrict__ W_hh_0,
                             const float* __restrict__ b_ih_0,
                             const float* __restrict__ b_hh_0,
                             const float* __restrict__ W_ih_1,
                             const float* __restrict__ W_hh_1,
                             const float* __restrict__ b_ih_1,
                             const float* __restrict__ b_hh_1,
                             float* __restrict__ ws) {
    int idx = blockIdx.x * blockDim.x + threadIdx.x;
    if (idx < WT1_OFF) {                       // WT0[k][g]
        int k = idx / GATES, g = idx % GATES;
        ws[idx] = (k < INPUT_DIM) ? W_ih_0[g * INPUT_DIM + k]
                                  : W_hh_0[g * HIDDEN + (k - INPUT_DIM)];
    } else if (idx < B0_OFF) {                 // WT1[k][g]
        int j = idx - WT1_OFF;
        int k = j / GATES, g = j % GATES;
        ws[idx] = (k < HIDDEN) ? W_ih_1[g * HIDDEN + k]
                               : W_hh_1[g * HIDDEN + (k - HIDDEN)];
    } else if (idx < B1_OFF) {
        int g = idx - B0_OFF;
        ws[idx] = b_ih_0[g] + b_hh_0[g];
    } else if (idx < WS_FLOATS) {
        int g = idx - B1_OFF;
        ws[idx] = b_ih_1[g] + b_hh_1[g];
    }
}

// ---------------- math helpers ----------------
__device__ __forceinline__ float sigm(float x) {
    return 1.0f / (1.0f + __expf(-x));        // x<<0: expf->inf, 1/inf=0 (safe)
}
__device__ __forceinline__ float tanh_fast(float x) {
    float ax = fabsf(x);
    float e  = __expf(-2.0f * ax);            // in (0,1], no overflow
    float t  = (1.0f - e) / (1.0f + e);
    return copysignf(t, x);
}

// K-loop: acc[4b][8g] += A[b0+bi][k] * WT[k][g-slice]
// 8 gates per thread = 2 hidden units (u0,u0+1) x 4 gate types (i,f,g,o)
template<int KLEN, int ROWLEN>
__device__ __forceinline__ void gemm_accum(const float* __restrict__ src, int b0,
                                           const float* __restrict__ w, int u0,
                                           float acc[4][8]) {
#pragma unroll 4
    for (int k = 0; k < KLEN; ++k) {
        const float* wrow = w + k * GATES + u0;
        float2 w0 = *(const float2*)(wrow);
        float2 w1 = *(const float2*)(wrow + 128);
        float2 w2 = *(const float2*)(wrow + 256);
        float2 w3 = *(const float2*)(wrow + 384);
        float a[4];
#pragma unroll
        for (int bi = 0; bi < 4; ++bi) a[bi] = src[(b0 + bi) * ROWLEN + k];  // LDS broadcast
#pragma unroll
        for (int bi = 0; bi < 4; ++bi) {
            acc[bi][0] = fmaf(a[bi], w0.x, acc[bi][0]);
            acc[bi][1] = fmaf(a[bi], w0.y, acc[bi][1]);
            acc[bi][2] = fmaf(a[bi], w1.x, acc[bi][2]);
            acc[bi][3] = fmaf(a[bi], w1.y, acc[bi][3]);
            acc[bi][4] = fmaf(a[bi], w2.x, acc[bi][4]);
            acc[bi][5] = fmaf(a[bi], w2.y, acc[bi][5]);
            acc[bi][6] = fmaf(a[bi], w3.x, acc[bi][6]);
            acc[bi][7] = fmaf(a[bi], w3.y, acc[bi][7]);
        }
    }
}

__device__ __forceinline__ void bias_init(const float* __restrict__ bias, int u0,
                                          float acc[4][8]) {
#pragma unroll
    for (int ty = 0; ty < 4; ++ty) {
        float2 bb = *(const float2*)(bias + ty * HIDDEN + u0);
#pragma unroll
        for (int bi = 0; bi < 4; ++bi) { acc[bi][ty * 2] = bb.x; acc[bi][ty * 2 + 1] = bb.y; }
    }
}

// gate order i,f,g,o (PyTorch); acc[bi][ty*2+ui]
__device__ __forceinline__ void cell_update(const float acc[4][8], float c[4][2],
                                            float hnew[4][2]) {
#pragma unroll
    for (int bi = 0; bi < 4; ++bi) {
#pragma unroll
        for (int ui = 0; ui < 2; ++ui) {
            float ig = sigm(acc[bi][0 + ui]);
            float fg = sigm(acc[bi][2 + ui]);
            float gg = tanh_fast(acc[bi][4 + ui]);
            float og = sigm(acc[bi][6 + ui]);
            float cn = fg * c[bi][ui] + ig * gg;
            c[bi][ui]    = cn;
            hnew[bi][ui] = og * tanh_fast(cn);
        }
    }
}

// ---------------- persistent per-batch-tile LSTM ----------------
__global__ __launch_bounds__(NTHREADS, 2)
void lstm_kernel(const float* __restrict__ input,   // [B,60,8]
                 const float* __restrict__ ws,
                 const float* __restrict__ W_fc,    // [1,128]
                 const float* __restrict__ b_fc,    // [1]
                 float* __restrict__ out) {         // [B,12]
    __shared__ float h0s[TILE_B][HIDDEN];
    __shared__ float h1s[TILE_B][HIDDEN];
    __shared__ float xs[TILE_B][INPUT_DIM];
    __shared__ float preds[TILE_B];
    __shared__ float wfcs[HIDDEN];

    const int tid = threadIdx.x;
    const int tu  = tid & 63;       // lane
    const int tb  = tid >> 6;       // wave id 0..7
    const int u0  = tu * 2;         // hidden-unit pair base 0..126
    const int b0  = tb * 4;         // 4 batch rows per thread
    const int batch0 = blockIdx.x * TILE_B;

    const float* wt0   = ws + WT0_OFF;
    const float* wt1   = ws + WT1_OFF;
    const float* bias0 = ws + B0_OFF;
    const float* bias1 = ws + B1_OFF;

    for (int i = tid; i < TILE_B * HIDDEN; i += NTHREADS) {
        ((float*)h0s)[i] = 0.0f;
        ((float*)h1s)[i] = 0.0f;
    }
    if (tid < HIDDEN) wfcs[tid] = W_fc[tid];
    const float bfc = b_fc[0];

    float c0r[4][2] = {};
    float c1r[4][2] = {};

    __syncthreads();

    for (int t = 0; t < TTOT; ++t) {
        // ---- stage x_t (with BG feedback for decoder steps > first) ----
        if (tid < TILE_B * INPUT_DIM) {
            int b = tid >> 3, k = tid & 7;
            float v = input[(size_t)(batch0 + b) * (TTOT * INPUT_DIM) + t * INPUT_DIM + k];
            if (t > LOOKBACK && k == 0) v = preds[b];
            xs[b][k] = v;
        }
        __syncthreads();                       // xs ready; prev h0/h1 ready

        // ---- layer 0: gates = x@Wih0^T + h0@Whh0^T + b ----
        float acc[4][8];
        bias_init(bias0, u0, acc);
        gemm_accum<INPUT_DIM, INPUT_DIM>(&xs[0][0], b0, wt0, u0, acc);
        gemm_accum<HIDDEN, HIDDEN>(&h0s[0][0], b0, wt0 + INPUT_DIM * GATES, u0, acc);
        float h0new[4][2];
        cell_update(acc, c0r, h0new);
        __syncthreads();                       // all reads of old h0 done
#pragma unroll
        for (int bi = 0; bi < 4; ++bi)
            *(float2*)&h0s[b0 + bi][u0] = make_float2(h0new[bi][0], h0new[bi][1]);
        __syncthreads();                       // new h0 visible

        // ---- layer 1: gates = h0@Wih1^T + h1@Whh1^T + b ----
        bias_init(bias1, u0, acc);
        gemm_accum<HIDDEN, HIDDEN>(&h0s[0][0], b0, wt1, u0, acc);
        gemm_accum<HIDDEN, HIDDEN>(&h1s[0][0], b0, wt1 + HIDDEN * GATES, u0, acc);
        float h1new[4][2];
        cell_update(acc, c1r, h1new);
        __syncthreads();                       // all reads of old h1 done
#pragma unroll
        for (int bi = 0; bi < 4; ++bi)
            *(float2*)&h1s[b0 + bi][u0] = make_float2(h1new[bi][0], h1new[bi][1]);

        if (t >= LOOKBACK) {
            __syncthreads();                   // new h1 visible for fc
            int dt  = t - LOOKBACK;
            int b   = tid >> 4;                // 16 threads per batch row
            int sub = tid & 15;
            float p = 0.0f;
            for (int u = sub; u < HIDDEN; u += 16) p += h1s[b][u] * wfcs[u];
#pragma unroll
            for (int off = 8; off; off >>= 1) p += __shfl_down(p, off, 16);
            if (sub == 0) {
                float pr = p + bfc;
                preds[b] = pr;
                out[(size_t)(batch0 + b) * HORIZON + dt] = pr;
            }
            __syncthreads();                   // preds visible before next stage
        }
        // encoder steps: next iteration's first __syncthreads covers h-visibility
    }
}

extern "C" void kernel_launch(void* const* d_in, const int* in_sizes, int n_in,
                              void* d_out, int out_size, void* d_ws, size_t ws_size,
                              hipStream_t stream) {
    const float* input  = (const float*)d_in[0];
    const float* W_ih_0 = (const float*)d_in[1];
    const float* W_hh_0 = (const float*)d_in[2];
    const float* b_ih_0 = (const float*)d_in[3];
    const float* b_hh_0 = (const float*)d_in[4];
    const float* W_ih_1 = (const float*)d_in[5];
    const float* W_hh_1 = (const float*)d_in[6];
    const float* b_ih_1 = (const float*)d_in[7];
    const float* b_hh_1 = (const float*)d_in[8];
    const float* W_fc   = (const float*)d_in[9];
    const float* b_fc   = (const float*)d_in[10];
    float* ws = (float*)d_ws;

    setup_kernel<<<(WS_FLOATS + 255) / 256, 256, 0, stream>>>(
        W_ih_0, W_hh_0, b_ih_0, b_hh_0, W_ih_1, W_hh_1, b_ih_1, b_hh_1, ws);

    lstm_kernel<<<BATCH / TILE_B, NTHREADS, 0, stream>>>(
        input, ws, W_fc, b_fc, (float*)d_out);
}

// Round 2
// 4386.588 us; speedup vs baseline: 1.2559x; 1.2559x over previous
//
#include <hip/hip_runtime.h>

#define LOOKBACK 48
#define HORIZON  12
#define TTOT     60
#define INPUT_DIM 8
#define HIDDEN   128
#define GATES    512   /* 4*HIDDEN */
#define BATCH    8192
#define TILE_B   16
#define NTHREADS 256

/* d_ws float layout.
   Weights stored transposed + gate-interleaved: WT[k][u*4 + t], t in {i,f,g,o}
   so one thread's 4 gates for unit u are a single float4, and lane-consecutive
   units give perfectly coalesced 16B/lane loads. */
#define WT0_K    (INPUT_DIM + HIDDEN)          /* 136: k<8 -> W_ih_0, else W_hh_0 */
#define WT0_OFF  0
#define WT1_K    (2 * HIDDEN)                  /* 256: k<128 -> W_ih_1, else W_hh_1 */
#define WT1_OFF  (WT0_K * GATES)               /* 69632 */
#define B0_OFF   (WT1_OFF + WT1_K * GATES)     /* 200704 */
#define B1_OFF   (B0_OFF + GATES)
#define WS_FLOATS (B1_OFF + GATES)             /* 201728 floats ~ 807 KB */

// ---------------- setup: transpose + gate-interleave weights, fuse biases ----------------
__global__ void setup_kernel(const float* __restrict__ W_ih_0,
                             const float* __restrict__ W_hh_0,
                             const float* __restrict__ b_ih_0,
                             const float* __restrict__ b_hh_0,
                             const float* __restrict__ W_ih_1,
                             const float* __restrict__ W_hh_1,
                             const float* __restrict__ b_ih_1,
                             const float* __restrict__ b_hh_1,
                             float* __restrict__ ws) {
    int idx = blockIdx.x * blockDim.x + threadIdx.x;
    if (idx < WT1_OFF) {                       // WT0[k][u*4+t]
        int k = idx / GATES, g = idx % GATES;
        int u = g >> 2, t = g & 3;
        int row = t * HIDDEN + u;              // original gate row (PyTorch i,f,g,o)
        ws[idx] = (k < INPUT_DIM) ? W_ih_0[row * INPUT_DIM + k]
                                  : W_hh_0[row * HIDDEN + (k - INPUT_DIM)];
    } else if (idx < B0_OFF) {                 // WT1[k][u*4+t]
        int j = idx - WT1_OFF;
        int k = j / GATES, g = j % GATES;
        int u = g >> 2, t = g & 3;
        int row = t * HIDDEN + u;
        ws[idx] = (k < HIDDEN) ? W_ih_1[row * HIDDEN + k]
                               : W_hh_1[row * HIDDEN + (k - HIDDEN)];
    } else if (idx < B1_OFF) {
        int g = idx - B0_OFF;
        int u = g >> 2, t = g & 3;
        int row = t * HIDDEN + u;
        ws[idx] = b_ih_0[row] + b_hh_0[row];
    } else if (idx < WS_FLOATS) {
        int g = idx - B1_OFF;
        int u = g >> 2, t = g & 3;
        int row = t * HIDDEN + u;
        ws[idx] = b_ih_1[row] + b_hh_1[row];
    }
}

// ---------------- math helpers ----------------
__device__ __forceinline__ float sigm(float x) {
    return 1.0f / (1.0f + __expf(-x));
}
__device__ __forceinline__ float tanh_fast(float x) {
    float ax = fabsf(x);
    float e  = __expf(-2.0f * ax);            // in (0,1], no overflow
    float t  = (1.0f - e) / (1.0f + e);
    return copysignf(t, x);
}

// K-loop: acc[8 rows][4 gates] += A[b0+bi][k] * WT[k][u*4 + {0..3}]
// A comes from LDS (wave-uniform broadcast, vectorized float4 over k);
// W from global (L1/L2-resident), one float4 per k per thread.
// 2-deep software pipeline: prefetch quad q+1 while computing quad q.
template<int NQ, int ROWLEN>
__device__ __forceinline__ void gemm_accum(const float* __restrict__ src, int b0,
                                           const float* __restrict__ w, int u4,
                                           float acc[8][4]) {
    const float* wp = w + u4;

    float4 wA[4], aA[8], wB[4], aB[8];

#define LOADW(q, dst)                                                     \
    _Pragma("unroll")                                                     \
    for (int j = 0; j < 4; ++j)                                           \
        dst[j] = *(const float4*)(wp + ((q) * 4 + j) * GATES);
#define LOADA(q, dst)                                                     \
    _Pragma("unroll")                                                     \
    for (int bi = 0; bi < 8; ++bi)                                        \
        dst[bi] = *(const float4*)(src + (b0 + bi) * ROWLEN + (q) * 4);
#define COMP(wv, av)                                                      \
    _Pragma("unroll")                                                     \
    for (int bi = 0; bi < 8; ++bi) {                                      \
        acc[bi][0] = fmaf(av[bi].x, wv[0].x, acc[bi][0]);                 \
        acc[bi][1] = fmaf(av[bi].x, wv[0].y, acc[bi][1]);                 \
        acc[bi][2] = fmaf(av[bi].x, wv[0].z, acc[bi][2]);                 \
        acc[bi][3] = fmaf(av[bi].x, wv[0].w, acc[bi][3]);                 \
        acc[bi][0] = fmaf(av[bi].y, wv[1].x, acc[bi][0]);                 \
        acc[bi][1] = fmaf(av[bi].y, wv[1].y, acc[bi][1]);                 \
        acc[bi][2] = fmaf(av[bi].y, wv[1].z, acc[bi][2]);                 \
        acc[bi][3] = fmaf(av[bi].y, wv[1].w, acc[bi][3]);                 \
        acc[bi][0] = fmaf(av[bi].z, wv[2].x, acc[bi][0]);                 \
        acc[bi][1] = fmaf(av[bi].z, wv[2].y, acc[bi][1]);                 \
        acc[bi][2] = fmaf(av[bi].z, wv[2].z, acc[bi][2]);                 \
        acc[bi][3] = fmaf(av[bi].z, wv[2].w, acc[bi][3]);                 \
        acc[bi][0] = fmaf(av[bi].w, wv[3].x, acc[bi][0]);                 \
        acc[bi][1] = fmaf(av[bi].w, wv[3].y, acc[bi][1]);                 \
        acc[bi][2] = fmaf(av[bi].w, wv[3].z, acc[bi][2]);                 \
        acc[bi][3] = fmaf(av[bi].w, wv[3].w, acc[bi][3]);                 \
    }

    LOADW(0, wA)
    LOADA(0, aA)
#pragma unroll 1
    for (int q = 0; q < NQ; q += 2) {
        if (q + 1 < NQ) { LOADW(q + 1, wB) LOADA(q + 1, aB) }
        COMP(wA, aA)
        if (q + 2 < NQ) { LOADW(q + 2, wA) LOADA(q + 2, aA) }
        if (q + 1 < NQ) { COMP(wB, aB) }
    }
#undef LOADW
#undef LOADA
#undef COMP
}

// gate order i,f,g,o; one hidden unit x 8 batch rows per thread
__device__ __forceinline__ void cell_update8(const float acc[8][4], float c[8],
                                             float hnew[8]) {
#pragma unroll
    for (int bi = 0; bi < 8; ++bi) {
        float ig = sigm(acc[bi][0]);
        float fg = sigm(acc[bi][1]);
        float gg = tanh_fast(acc[bi][2]);
        float og = sigm(acc[bi][3]);
        float cn = fg * c[bi] + ig * gg;
        c[bi]    = cn;
        hnew[bi] = og * tanh_fast(cn);
    }
}

// ---------------- persistent per-batch-tile LSTM ----------------
// 256 threads = 4 waves; thread owns unit u = tid&127 for 8 batch rows.
// grid = 512 blocks -> 2 blocks/CU (independent barrier domains).
__global__ __launch_bounds__(NTHREADS, 2)
void lstm_kernel(const float* __restrict__ input,   // [B,60,8]
                 const float* __restrict__ ws,
                 const float* __restrict__ W_fc,    // [1,128]
                 const float* __restrict__ b_fc,    // [1]
                 float* __restrict__ out) {         // [B,12]
    __shared__ float h0s[TILE_B][HIDDEN];
    __shared__ float h1s[TILE_B][HIDDEN];
    __shared__ float xs[TILE_B][INPUT_DIM];
    __shared__ float preds[TILE_B];
    __shared__ float wfcs[HIDDEN];

    const int tid = threadIdx.x;
    const int u   = tid & 127;
    const int u4  = u * 4;
    const int b0  = (tid >> 7) * 8;            // rows b0..b0+7
    const int batch0 = blockIdx.x * TILE_B;

    const float* wt0x  = ws + WT0_OFF;                       // K=8
    const float* wt0h  = ws + WT0_OFF + INPUT_DIM * GATES;   // K=128
    const float* wt1a  = ws + WT1_OFF;                       // K=128 (input h0)
    const float* wt1b  = ws + WT1_OFF + HIDDEN * GATES;      // K=128 (recurrent h1)
    const float* bias0 = ws + B0_OFF;
    const float* bias1 = ws + B1_OFF;

    for (int i = tid; i < TILE_B * HIDDEN; i += NTHREADS) {
        ((float*)h0s)[i] = 0.0f;
        ((float*)h1s)[i] = 0.0f;
    }
    if (tid < HIDDEN) wfcs[tid] = W_fc[tid];
    const float bfc = b_fc[0];

    float c0r[8] = {};
    float c1r[8] = {};

    __syncthreads();

    for (int t = 0; t < TTOT; ++t) {
        // ---- stage x_t (BG feedback for decoder steps after the first) ----
        if (tid < TILE_B * INPUT_DIM) {
            int b = tid >> 3, k = tid & 7;
            float v = input[(size_t)(batch0 + b) * (TTOT * INPUT_DIM) + t * INPUT_DIM + k];
            if (t > LOOKBACK && k == 0) v = preds[b];
            xs[b][k] = v;
        }
        __syncthreads();                       // xs ready; prev h0/h1 visible

        // ---- layer 0: gates = x@Wih0^T + h0@Whh0^T + b ----
        float acc[8][4];
        {
            float4 bb = *(const float4*)(bias0 + u4);
#pragma unroll
            for (int bi = 0; bi < 8; ++bi) {
                acc[bi][0] = bb.x; acc[bi][1] = bb.y; acc[bi][2] = bb.z; acc[bi][3] = bb.w;
            }
        }
        gemm_accum<2, INPUT_DIM>(&xs[0][0], b0, wt0x, u4, acc);
        gemm_accum<32, HIDDEN>(&h0s[0][0], b0, wt0h, u4, acc);
        float h0new[8];
        cell_update8(acc, c0r, h0new);
        __syncthreads();                       // all reads of old h0 done
#pragma unroll
        for (int bi = 0; bi < 8; ++bi) h0s[b0 + bi][u] = h0new[bi];
        __syncthreads();                       // new h0 visible

        // ---- layer 1: gates = h0@Wih1^T + h1@Whh1^T + b ----
        {
            float4 bb = *(const float4*)(bias1 + u4);
#pragma unroll
            for (int bi = 0; bi < 8; ++bi) {
                acc[bi][0] = bb.x; acc[bi][1] = bb.y; acc[bi][2] = bb.z; acc[bi][3] = bb.w;
            }
        }
        gemm_accum<32, HIDDEN>(&h0s[0][0], b0, wt1a, u4, acc);
        gemm_accum<32, HIDDEN>(&h1s[0][0], b0, wt1b, u4, acc);
        float h1new[8];
        cell_update8(acc, c1r, h1new);
        __syncthreads();                       // all reads of old h1 done
#pragma unroll
        for (int bi = 0; bi < 8; ++bi) h1s[b0 + bi][u] = h1new[bi];

        if (t >= LOOKBACK) {
            __syncthreads();                   // new h1 visible for fc
            int dt  = t - LOOKBACK;
            int b   = tid >> 4;                // 16 threads per batch row
            int sub = tid & 15;
            float p = 0.0f;
#pragma unroll
            for (int it = 0; it < HIDDEN / 16; ++it) p += h1s[b][sub + it * 16] * wfcs[sub + it * 16];
#pragma unroll
            for (int off = 8; off; off >>= 1) p += __shfl_down(p, off, 16);
            if (sub == 0) {
                float pr = p + bfc;
                preds[b] = pr;
                out[(size_t)(batch0 + b) * HORIZON + dt] = pr;
            }
            __syncthreads();                   // preds visible before next stage
        }
        // encoder steps: next iteration's first __syncthreads covers h-visibility
    }
}

extern "C" void kernel_launch(void* const* d_in, const int* in_sizes, int n_in,
                              void* d_out, int out_size, void* d_ws, size_t ws_size,
                              hipStream_t stream) {
    const float* input  = (const float*)d_in[0];
    const float* W_ih_0 = (const float*)d_in[1];
    const float* W_hh_0 = (const float*)d_in[2];
    const float* b_ih_0 = (const float*)d_in[3];
    const float* b_hh_0 = (const float*)d_in[4];
    const float* W_ih_1 = (const float*)d_in[5];
    const float* W_hh_1 = (const float*)d_in[6];
    const float* b_ih_1 = (const float*)d_in[7];
    const float* b_hh_1 = (const float*)d_in[8];
    const float* W_fc   = (const float*)d_in[9];
    const float* b_fc   = (const float*)d_in[10];
    float* ws = (float*)d_ws;

    setup_kernel<<<(WS_FLOATS + 255) / 256, 256, 0, stream>>>(
        W_ih_0, W_hh_0, b_ih_0, b_hh_0, W_ih_1, W_hh_1, b_ih_1, b_hh_1, ws);

    lstm_kernel<<<BATCH / TILE_B, NTHREADS, 0, stream>>>(
        input, ws, W_fc, b_fc, (float*)d_out);
}

// Round 3
// 1928.511 us; speedup vs baseline: 2.8568x; 2.2746x over previous
//
#include <hip/hip_runtime.h>

#define LOOKBACK 48
#define HORIZON  12
#define TTOT     60
#define INPUT_DIM 8
#define HIDDEN   128
#define GATES    512
#define BATCH    8192
#define TILE_B   32          /* batch rows per block (2 M-tiles of 16) */
#define NTHREADS 512         /* 8 waves; wave s owns hidden units s*16..s*16+15 */
#define NSLICES  8
#define L0_KS    5           /* layer0 K = 160 (8 x + 128 h0 + 24 zero-pad) */
#define L1_KS    8           /* layer1 K = 256 (128 h0 + 128 h1) */
#define FRAGS_PER_KS 8       /* 4 gate-type N-tiles x {hi,lo} */
#define FRAG_SHORTS 512      /* 1KB per fragment */
#define SLICE_FRAGS ((L0_KS + L1_KS) * FRAGS_PER_KS)     /* 104 */
#define W_SHORTS (NSLICES * SLICE_FRAGS * FRAG_SHORTS)   /* 425984 shorts = 832KB */
/* float bias region appended after W frags: 512 (L0) + 512 (L1) floats */

/* A-plane LDS layout: [k8][ROWP rows][8 bf16], ROWP=33 (pad +1 row per chunk
   to break the 512B quad stride -> conflict-free ds_read_b128) */
#define ROWP 33
#define A0_CHUNKS 20         /* K=160 */
#define A1_CHUNKS 32         /* K=256 */
#define A0_SHORTS (A0_CHUNKS * ROWP * 8)   /* 5280 */
#define A1_SHORTS (A1_CHUNKS * ROWP * 8)   /* 8448 */

typedef __attribute__((ext_vector_type(8))) short short8;
typedef __attribute__((ext_vector_type(4))) float f32x4;

__device__ __forceinline__ unsigned short bf16_rn(float v) {
    unsigned int x = __float_as_uint(v);
    unsigned int r = x + 0x7fffu + ((x >> 16) & 1u);
    return (unsigned short)(r >> 16);
}
__device__ __forceinline__ float bf16_to_f(unsigned short h) {
    return __uint_as_float(((unsigned int)h) << 16);
}
__device__ __forceinline__ float sigm(float x) {
    return 1.0f / (1.0f + __expf(-x));
}
__device__ __forceinline__ float tanh_fast(float x) {
    float ax = fabsf(x);
    float e  = __expf(-2.0f * ax);
    float t  = (1.0f - e) / (1.0f + e);
    return copysignf(t, x);
}

// ------------- setup: split weights hi/lo bf16, store in MFMA-fragment order -------------
// frag element (lane, j) holds W_l[k = ks*32 + (lane>>4)*8 + j][gate row = t*128 + s*16 + (lane&15)]
__global__ void setup_kernel(const float* __restrict__ Wih0, const float* __restrict__ Whh0,
                             const float* __restrict__ bi0,  const float* __restrict__ bh0,
                             const float* __restrict__ Wih1, const float* __restrict__ Whh1,
                             const float* __restrict__ bi1,  const float* __restrict__ bh1,
                             unsigned short* __restrict__ wfrag, float* __restrict__ bias) {
    int idx = blockIdx.x * blockDim.x + threadIdx.x;
    if (idx < W_SHORTS) {
        int e = idx & 511, frag = idx >> 9;
        int lane = e >> 3, j = e & 7;
        int p = frag & 1, t = (frag >> 1) & 3;
        int rest = frag >> 3;
        int lks = rest % (L0_KS + L1_KS), s = rest / (L0_KS + L1_KS);
        int l = (lks < L0_KS) ? 0 : 1;
        int ks = l ? (lks - L0_KS) : lks;
        int k = ks * 32 + ((lane >> 4) << 3) + j;
        int u = s * 16 + (lane & 15);
        int row = t * HIDDEN + u;
        float v = 0.0f;
        if (l == 0) {
            if (k < INPUT_DIM) v = Wih0[row * INPUT_DIM + k];
            else if (k < INPUT_DIM + HIDDEN) v = Whh0[row * HIDDEN + (k - INPUT_DIM)];
            /* k >= 136: zero pad */
        } else {
            if (k < HIDDEN) v = Wih1[row * HIDDEN + k];
            else v = Whh1[row * HIDDEN + (k - HIDDEN)];
        }
        unsigned short hi = bf16_rn(v);
        wfrag[idx] = (p == 0) ? hi : bf16_rn(v - bf16_to_f(hi));
    } else if (idx < W_SHORTS + 2 * GATES) {
        int g = idx - W_SHORTS;
        bias[g] = (g < GATES) ? (bi0[g] + bh0[g]) : (bi1[g - GATES] + bh1[g - GATES]);
    }
}

// ------------- split-bf16 MFMA GEMM over one layer's K -------------
// acc[mt][t] : M-tile mt (batch rows mt*16..+15), gate-type t. 24 MFMA per K-step.
template<int NKS>
__device__ __forceinline__ void gemm(f32x4 acc[2][4],
                                     const unsigned short* __restrict__ Ahi,
                                     const unsigned short* __restrict__ Alo,
                                     const unsigned short* __restrict__ wbase,
                                     int lane) {
    const int col = lane & 15, quad = lane >> 4;
    short8 ah[2][2], al[2][2], bh[2][4], bl[2][4];

#define LOADA(ks, buf)                                                          \
    {   int base = (((ks) * 4 + quad) * ROWP + col) * 8;                        \
        ah[buf][0] = *(const short8*)(Ahi + base);                              \
        ah[buf][1] = *(const short8*)(Ahi + base + 16 * 8);                     \
        al[buf][0] = *(const short8*)(Alo + base);                              \
        al[buf][1] = *(const short8*)(Alo + base + 16 * 8); }
#define LOADB(ks, buf)                                                          \
    {   const unsigned short* wp = wbase + (ks) * (FRAGS_PER_KS * FRAG_SHORTS)  \
                                   + lane * 8;                                  \
        _Pragma("unroll")                                                       \
        for (int tt = 0; tt < 4; ++tt) {                                        \
            bh[buf][tt] = *(const short8*)(wp + (tt * 2) * FRAG_SHORTS);        \
            bl[buf][tt] = *(const short8*)(wp + (tt * 2 + 1) * FRAG_SHORTS);    \
        } }
#define COMP(buf)                                                               \
    _Pragma("unroll")                                                           \
    for (int tt = 0; tt < 4; ++tt)                                              \
        _Pragma("unroll")                                                       \
        for (int mt = 0; mt < 2; ++mt) {                                        \
            acc[mt][tt] = __builtin_amdgcn_mfma_f32_16x16x32_bf16(              \
                ah[buf][mt], bh[buf][tt], acc[mt][tt], 0, 0, 0);                \
            acc[mt][tt] = __builtin_amdgcn_mfma_f32_16x16x32_bf16(              \
                al[buf][mt], bh[buf][tt], acc[mt][tt], 0, 0, 0);                \
            acc[mt][tt] = __builtin_amdgcn_mfma_f32_16x16x32_bf16(              \
                ah[buf][mt], bl[buf][tt], acc[mt][tt], 0, 0, 0);                \
        }

    LOADB(0, 0) LOADA(0, 0)
#pragma unroll
    for (int ks = 0; ks < NKS; ++ks) {
        const int cur = ks & 1, nxt = cur ^ 1;
        if (ks + 1 < NKS) { LOADB(ks + 1, nxt) LOADA(ks + 1, nxt) }
        COMP(cur)
    }
#undef LOADA
#undef LOADB
#undef COMP
}

// ------------- persistent 2-layer LSTM, MFMA path -------------
__global__ __launch_bounds__(NTHREADS, 2)
void lstm_kernel(const float* __restrict__ input,   // [B,60,8]
                 const unsigned short* __restrict__ wfrag,
                 const float* __restrict__ bias01,  // [1024]
                 const float* __restrict__ W_fc,    // [128]
                 const float* __restrict__ b_fc,
                 float* __restrict__ out) {         // [B,12]
    __shared__ unsigned short A0hi[A0_SHORTS], A0lo[A0_SHORTS];
    __shared__ unsigned short A1hi[A1_SHORTS], A1lo[A1_SHORTS];
    __shared__ float preds[TILE_B];
    __shared__ float wfcs[HIDDEN];

    const int tid  = threadIdx.x;
    const int lane = tid & 63;
    const int s    = tid >> 6;          // wave = unit slice
    const int col  = lane & 15;
    const int quad = lane >> 4;
    const int u    = s * 16 + col;      // this lane's hidden unit
    const int batch0 = blockIdx.x * TILE_B;

    // zero A planes (h0 = h1 = 0 at t=0; zero-pad region stays zero forever)
    for (int i = tid; i < A0_SHORTS; i += NTHREADS) { A0hi[i] = 0; A0lo[i] = 0; }
    for (int i = tid; i < A1_SHORTS; i += NTHREADS) { A1hi[i] = 0; A1lo[i] = 0; }
    if (tid < HIDDEN) wfcs[tid] = W_fc[tid];
    const float bfc = b_fc[0];

    float bv0[4], bv1[4];
#pragma unroll
    for (int tt = 0; tt < 4; ++tt) {
        bv0[tt] = bias01[tt * HIDDEN + u];
        bv1[tt] = bias01[GATES + tt * HIDDEN + u];
    }

    float c0[2][4] = {}, c1[2][4] = {};

    const unsigned short* wslice = wfrag + s * (SLICE_FRAGS * FRAG_SHORTS);
    const unsigned short* w0 = wslice;
    const unsigned short* w1 = wslice + L0_KS * FRAGS_PER_KS * FRAG_SHORTS;

    __syncthreads();

    for (int t = 0; t < TTOT; ++t) {
        // ---- stage x_t into A0 chunk 0 (with BG feedback for t>48) ----
        if (tid < TILE_B * INPUT_DIM) {
            int r = tid >> 3, k = tid & 7;
            float v = input[(size_t)(batch0 + r) * (TTOT * INPUT_DIM) + t * INPUT_DIM + k];
            if (t > LOOKBACK && k == 0) v = preds[r];
            unsigned short hi = bf16_rn(v);
            int idx = r * 8 + k;               // k8=0 chunk
            A0hi[idx] = hi;
            A0lo[idx] = bf16_rn(v - bf16_to_f(hi));
        }
        __syncthreads();                        // B1: x ready, prev h ready

        // ---- layer 0 GEMM ----
        f32x4 acc[2][4];
#pragma unroll
        for (int tt = 0; tt < 4; ++tt) {
            f32x4 b = {bv0[tt], bv0[tt], bv0[tt], bv0[tt]};
            acc[0][tt] = b; acc[1][tt] = b;
        }
        gemm<L0_KS>(acc, A0hi, A0lo, w0, lane);
        __syncthreads();                        // B2: all L0 reads of A0 done

        // ---- cell update L0; write h0 into A0 (k=8+u) and A1 (k=u) ----
#pragma unroll
        for (int mt = 0; mt < 2; ++mt) {
#pragma unroll
            for (int r = 0; r < 4; ++r) {
                float ig = sigm(acc[mt][0][r]);
                float fg = sigm(acc[mt][1][r]);
                float gg = tanh_fast(acc[mt][2][r]);
                float og = sigm(acc[mt][3][r]);
                float cn = fg * c0[mt][r] + ig * gg;
                c0[mt][r] = cn;
                float h = og * tanh_fast(cn);
                unsigned short hi = bf16_rn(h);
                unsigned short lo = bf16_rn(h - bf16_to_f(hi));
                int row = mt * 16 + quad * 4 + r;
                int k0 = INPUT_DIM + u;
                int i0 = ((k0 >> 3) * ROWP + row) * 8 + (k0 & 7);
                A0hi[i0] = hi; A0lo[i0] = lo;
                int i1 = ((u >> 3) * ROWP + row) * 8 + (u & 7);
                A1hi[i1] = hi; A1lo[i1] = lo;
            }
        }
        __syncthreads();                        // B3: h0 new visible

        // ---- layer 1 GEMM ----
#pragma unroll
        for (int tt = 0; tt < 4; ++tt) {
            f32x4 b = {bv1[tt], bv1[tt], bv1[tt], bv1[tt]};
            acc[0][tt] = b; acc[1][tt] = b;
        }
        gemm<L1_KS>(acc, A1hi, A1lo, w1, lane);
        __syncthreads();                        // B4: all L1 reads of A1 done

        // ---- cell update L1; write h1 into A1 (k=128+u) ----
#pragma unroll
        for (int mt = 0; mt < 2; ++mt) {
#pragma unroll
            for (int r = 0; r < 4; ++r) {
                float ig = sigm(acc[mt][0][r]);
                float fg = sigm(acc[mt][1][r]);
                float gg = tanh_fast(acc[mt][2][r]);
                float og = sigm(acc[mt][3][r]);
                float cn = fg * c1[mt][r] + ig * gg;
                c1[mt][r] = cn;
                float h = og * tanh_fast(cn);
                unsigned short hi = bf16_rn(h);
                unsigned short lo = bf16_rn(h - bf16_to_f(hi));
                int row = mt * 16 + quad * 4 + r;
                int k1 = HIDDEN + u;
                int i1 = ((k1 >> 3) * ROWP + row) * 8 + (k1 & 7);
                A1hi[i1] = hi; A1lo[i1] = lo;
            }
        }

        // ---- decode: fc head + BG feedback ----
        if (t >= LOOKBACK) {
            __syncthreads();                    // B5: h1 new visible
            int r = tid >> 4, sub = tid & 15;
            float p = 0.0f;
#pragma unroll
            for (int i = 0; i < HIDDEN / 16; ++i) {
                int uu = sub + i * 16;
                int k = HIDDEN + uu;
                int idx = ((k >> 3) * ROWP + r) * 8 + (k & 7);
                p += (bf16_to_f(A1hi[idx]) + bf16_to_f(A1lo[idx])) * wfcs[uu];
            }
#pragma unroll
            for (int off = 8; off; off >>= 1) p += __shfl_down(p, off, 16);
            if (sub == 0) {
                float pr = p + bfc;
                preds[r] = pr;
                out[(size_t)(batch0 + r) * HORIZON + (t - LOOKBACK)] = pr;
            }
            __syncthreads();                    // B6: preds visible for next x-stage
        }
    }
}

extern "C" void kernel_launch(void* const* d_in, const int* in_sizes, int n_in,
                              void* d_out, int out_size, void* d_ws, size_t ws_size,
                              hipStream_t stream) {
    const float* input = (const float*)d_in[0];
    const float* Wih0  = (const float*)d_in[1];
    const float* Whh0  = (const float*)d_in[2];
    const float* bi0   = (const float*)d_in[3];
    const float* bh0   = (const float*)d_in[4];
    const float* Wih1  = (const float*)d_in[5];
    const float* Whh1  = (const float*)d_in[6];
    const float* bi1   = (const float*)d_in[7];
    const float* bh1   = (const float*)d_in[8];
    const float* W_fc  = (const float*)d_in[9];
    const float* b_fc  = (const float*)d_in[10];

    unsigned short* wfrag = (unsigned short*)d_ws;
    float* bias = (float*)((char*)d_ws + (size_t)W_SHORTS * sizeof(unsigned short));

    int total = W_SHORTS + 2 * GATES;
    setup_kernel<<<(total + 255) / 256, 256, 0, stream>>>(
        Wih0, Whh0, bi0, bh0, Wih1, Whh1, bi1, bh1, wfrag, bias);

    lstm_kernel<<<BATCH / TILE_B, NTHREADS, 0, stream>>>(
        input, wfrag, bias, W_fc, b_fc, (float*)d_out);
}

// Round 4
// 1709.587 us; speedup vs baseline: 3.2226x; 1.1281x over previous
//
#include <hip/hip_runtime.h>

#define LOOKBACK 48
#define HORIZON  12
#define TTOT     60
#define INPUT_DIM 8
#define HIDDEN   128
#define GATES    512
#define BATCH    8192
#define TILE_B   32          /* batch rows per block (2 M-tiles of 16) */
#define NTHREADS 512         /* 8 waves; wave s owns hidden units s*16..s*16+15 */
#define NSLICES  8
#define L0_KS    5           /* layer0 K = 160 (8 x + 128 h0 + 24 zero-pad) */
#define L1_KS    8           /* layer1 K = 256 (128 h0 + 128 h1) */
#define FRAGS_PER_KS 8       /* 4 gate-type N-tiles x {hi,lo} */
#define FRAG_SHORTS 512      /* 1KB per fragment */
#define KSTRIDE  (FRAGS_PER_KS * FRAG_SHORTS)            /* 4096 shorts per K-step */
#define SLICE_FRAGS ((L0_KS + L1_KS) * FRAGS_PER_KS)     /* 104 */
#define W_SHORTS (NSLICES * SLICE_FRAGS * FRAG_SHORTS)   /* 425984 shorts = 832KB */

/* A-plane LDS layout: [chunk][ROWP rows][8 bf16], ROWP=33.
   A0: chunk0 = x (k=0..7), chunks 1..16 = h0 (k=8+u), chunks 17..19 = zero pad.
   A1: chunks 0..15 = h1 (k=128+u for layer-1 GEMM).
   Layer-1 GEMM reads its h0-part (k=0..127) directly from A0 chunks 1..16. */
#define ROWP 33
#define A0_CHUNKS 20
#define A1_CHUNKS 16
#define A0_SHORTS (A0_CHUNKS * ROWP * 8)   /* 5280 */
#define A1_SHORTS (A1_CHUNKS * ROWP * 8)   /* 4224 */

typedef __attribute__((ext_vector_type(8))) short short8;
typedef __attribute__((ext_vector_type(4))) float f32x4;

__device__ __forceinline__ unsigned short bf16_rn(float v) {
    unsigned int x = __float_as_uint(v);
    unsigned int r = x + 0x7fffu + ((x >> 16) & 1u);
    return (unsigned short)(r >> 16);
}
__device__ __forceinline__ float bf16_to_f(unsigned short h) {
    return __uint_as_float(((unsigned int)h) << 16);
}
__device__ __forceinline__ float sigm(float x) {
    return 1.0f / (1.0f + __expf(-x));
}
__device__ __forceinline__ float tanh_fast(float x) {
    float ax = fabsf(x);
    float e  = __expf(-2.0f * ax);
    float t  = (1.0f - e) / (1.0f + e);
    return copysignf(t, x);
}

/* Barrier WITHOUT vmcnt drain: LDS ordering via lgkmcnt(0), global prefetch
   loads stay in flight across the barrier (the m97 ~20% stall killer). */
#define BARRIER() __asm__ volatile("s_waitcnt lgkmcnt(0)\ns_barrier" ::: "memory")

// ------------- setup: split weights hi/lo bf16, store in MFMA-fragment order -------------
__global__ void setup_kernel(const float* __restrict__ Wih0, const float* __restrict__ Whh0,
                             const float* __restrict__ bi0,  const float* __restrict__ bh0,
                             const float* __restrict__ Wih1, const float* __restrict__ Whh1,
                             const float* __restrict__ bi1,  const float* __restrict__ bh1,
                             unsigned short* __restrict__ wfrag, float* __restrict__ bias) {
    int idx = blockIdx.x * blockDim.x + threadIdx.x;
    if (idx < W_SHORTS) {
        int e = idx & 511, frag = idx >> 9;
        int lane = e >> 3, j = e & 7;
        int p = frag & 1, t = (frag >> 1) & 3;
        int rest = frag >> 3;
        int lks = rest % (L0_KS + L1_KS), s = rest / (L0_KS + L1_KS);
        int l = (lks < L0_KS) ? 0 : 1;
        int ks = l ? (lks - L0_KS) : lks;
        int k = ks * 32 + ((lane >> 4) << 3) + j;
        int uu = s * 16 + (lane & 15);
        int row = t * HIDDEN + uu;
        float v = 0.0f;
        if (l == 0) {
            if (k < INPUT_DIM) v = Wih0[row * INPUT_DIM + k];
            else if (k < INPUT_DIM + HIDDEN) v = Whh0[row * HIDDEN + (k - INPUT_DIM)];
        } else {
            if (k < HIDDEN) v = Wih1[row * HIDDEN + k];
            else v = Whh1[row * HIDDEN + (k - HIDDEN)];
        }
        unsigned short hi = bf16_rn(v);
        wfrag[idx] = (p == 0) ? hi : bf16_rn(v - bf16_to_f(hi));
    } else if (idx < W_SHORTS + 2 * GATES) {
        int g = idx - W_SHORTS;
        bias[g] = (g < GATES) ? (bi0[g] + bh0[g]) : (bi1[g - GATES] + bh1[g - GATES]);
    }
}

// ------------- persistent 2-layer LSTM, MFMA + conveyor -------------
__global__ __launch_bounds__(NTHREADS, 2)
void lstm_kernel(const float* __restrict__ input,   // [B,60,8]
                 const unsigned short* __restrict__ wfrag,
                 const float* __restrict__ bias01,  // [1024]
                 const float* __restrict__ W_fc,    // [128]
                 const float* __restrict__ b_fc,
                 float* __restrict__ out) {         // [B,12]
    __shared__ unsigned short A0h[A0_SHORTS], A0l[A0_SHORTS];
    __shared__ unsigned short A1h_[A1_SHORTS], A1l_[A1_SHORTS];
    __shared__ float wfcs[HIDDEN];

    const int tid  = threadIdx.x;
    const int lane = tid & 63;
    const int s    = tid >> 6;
    const int col  = lane & 15;
    const int quad = lane >> 4;
    const int u    = s * 16 + col;
    const int uc   = 1 + (u >> 3);      // A0 chunk holding this lane's h0
    const int uo   = u & 7;
    const int batch0 = blockIdx.x * TILE_B;

    const unsigned short* w0 = wfrag + s * (SLICE_FRAGS * FRAG_SHORTS);
    const unsigned short* w1 = w0 + L0_KS * KSTRIDE;

    for (int i = tid; i < A0_SHORTS; i += NTHREADS) { A0h[i] = 0; A0l[i] = 0; }
    for (int i = tid; i < A1_SHORTS; i += NTHREADS) { A1h_[i] = 0; A1l_[i] = 0; }
    if (tid < HIDDEN) wfcs[tid] = W_fc[tid];
    const float bfc = b_fc[0];

    float bv0[4], bv1[4];
#pragma unroll
    for (int tt = 0; tt < 4; ++tt) {
        bv0[tt] = bias01[tt * HIDDEN + u];
        bv1[tt] = bias01[GATES + tt * HIDDEN + u];
    }

    float c0[2][4] = {}, c1[2][4] = {};

    // x(0) prefetch + stage
    float xv = 0.0f;
    if (tid < TILE_B * INPUT_DIM)
        xv = input[(size_t)(batch0 + (tid >> 3)) * (TTOT * INPUT_DIM) + (tid & 7)];
    BARRIER();                               // zero-init visible
    if (tid < TILE_B * INPUT_DIM) {
        int r = tid >> 3, k = tid & 7;
        unsigned short hi = bf16_rn(xv);
        A0h[r * 8 + k] = hi;
        A0l[r * 8 + k] = bf16_rn(xv - bf16_to_f(hi));
    }

    short8 bh[3][4], bl[3][4];               // B conveyor (depth 3)
    short8 ah[2][2], al[2][2];               // A double buffer

#define WPOS(p) ((p) < L0_KS ? (w0 + (p) * KSTRIDE) : (w1 + ((p) - L0_KS) * KSTRIDE))
#define LOADB(p, sl) { const unsigned short* wp_ = WPOS(p) + lane * 8;          \
    _Pragma("unroll") for (int tt = 0; tt < 4; ++tt) {                          \
        bh[sl][tt] = *(const short8*)(wp_ + (tt * 2) * FRAG_SHORTS);            \
        bl[sl][tt] = *(const short8*)(wp_ + (tt * 2 + 1) * FRAG_SHORTS); } }
#define LOADA(Hh, Hl, chunk, buf) { int base_ = (((chunk) * ROWP) + col) * 8;   \
    ah[buf][0] = *(const short8*)(Hh + base_);                                  \
    ah[buf][1] = *(const short8*)(Hh + base_ + 16 * 8);                         \
    al[buf][0] = *(const short8*)(Hl + base_);                                  \
    al[buf][1] = *(const short8*)(Hl + base_ + 16 * 8); }
#define COMP(ACC, ab, sl)                                                       \
    _Pragma("unroll") for (int tt = 0; tt < 4; ++tt)                            \
    _Pragma("unroll") for (int mt = 0; mt < 2; ++mt) {                          \
        ACC[mt][tt] = __builtin_amdgcn_mfma_f32_16x16x32_bf16(                  \
            ah[ab][mt], bh[sl][tt], ACC[mt][tt], 0, 0, 0);                      \
        ACC[mt][tt] = __builtin_amdgcn_mfma_f32_16x16x32_bf16(                  \
            al[ab][mt], bh[sl][tt], ACC[mt][tt], 0, 0, 0);                      \
        ACC[mt][tt] = __builtin_amdgcn_mfma_f32_16x16x32_bf16(                  \
            ah[ab][mt], bl[sl][tt], ACC[mt][tt], 0, 0, 0); }

    LOADB(0, 0) LOADB(1, 1) LOADB(2, 2)      // prime conveyor
    BARRIER();                               // x(0) staged & visible

#pragma unroll 1
    for (int t = 0; t < TTOT; ++t) {
        // prefetch x(t+1) into registers (consumed after B2)
        if (tid < TILE_B * INPUT_DIM && t + 1 < TTOT)
            xv = input[(size_t)(batch0 + (tid >> 3)) * (TTOT * INPUT_DIM)
                       + (t + 1) * INPUT_DIM + (tid & 7)];

        // ---- layer 0 GEMM: stream pos 0..4 ----
        f32x4 acc[2][4];
#pragma unroll
        for (int tt = 0; tt < 4; ++tt) {
            f32x4 b = {bv0[tt], bv0[tt], bv0[tt], bv0[tt]};
            acc[0][tt] = b; acc[1][tt] = b;
        }
        LOADA(A0h, A0l, quad, 0)
        LOADA(A0h, A0l, 4 + quad, 1)  COMP(acc, 0, 0) LOADB(3, 0)
        LOADA(A0h, A0l, 8 + quad, 0)  COMP(acc, 1, 1) LOADB(4, 1)
        LOADA(A0h, A0l, 12 + quad, 1) COMP(acc, 0, 2) LOADB(5, 2)
        LOADA(A0h, A0l, 16 + quad, 0) COMP(acc, 1, 0) LOADB(6, 0)
                                      COMP(acc, 0, 1) LOADB(7, 1)
        BARRIER();                           // B2: all A0 reads done

        // ---- cell 0 -> write h0 (A0 chunks 1..16); stage x(t+1) chunk 0 ----
#pragma unroll
        for (int mt = 0; mt < 2; ++mt) {
#pragma unroll
            for (int r = 0; r < 4; ++r) {
                float ig = sigm(acc[mt][0][r]);
                float fg = sigm(acc[mt][1][r]);
                float gg = tanh_fast(acc[mt][2][r]);
                float og = sigm(acc[mt][3][r]);
                float cn = fg * c0[mt][r] + ig * gg;
                c0[mt][r] = cn;
                float h = og * tanh_fast(cn);
                unsigned short hi = bf16_rn(h);
                int row = mt * 16 + quad * 4 + r;
                int i0 = (uc * ROWP + row) * 8 + uo;
                A0h[i0] = hi;
                A0l[i0] = bf16_rn(h - bf16_to_f(hi));
            }
        }
        if (tid < TILE_B * INPUT_DIM && t + 1 < TTOT) {
            int r = tid >> 3, k = tid & 7;
            if (!(t + 1 > LOOKBACK && k == 0)) {   // BG slot filled by fc instead
                unsigned short hi = bf16_rn(xv);
                A0h[r * 8 + k] = hi;
                A0l[r * 8 + k] = bf16_rn(xv - bf16_to_f(hi));
            }
        }
        BARRIER();                           // B3: h0(t) + x(t+1) visible

        // ---- layer 1 GEMM: stream pos 5..12 (h0 from A0, h1 from A1) ----
#pragma unroll
        for (int tt = 0; tt < 4; ++tt) {
            f32x4 b = {bv1[tt], bv1[tt], bv1[tt], bv1[tt]};
            acc[0][tt] = b; acc[1][tt] = b;
        }
        LOADA(A0h, A0l, 1 + quad, 0)
        LOADA(A0h, A0l, 5 + quad, 1)   COMP(acc, 0, 2) LOADB(8, 2)
        LOADA(A0h, A0l, 9 + quad, 0)   COMP(acc, 1, 0) LOADB(9, 0)
        LOADA(A0h, A0l, 13 + quad, 1)  COMP(acc, 0, 1) LOADB(10, 1)
        LOADA(A1h_, A1l_, quad, 0)     COMP(acc, 1, 2) LOADB(11, 2)
        LOADA(A1h_, A1l_, 4 + quad, 1) COMP(acc, 0, 0) LOADB(12, 0)
        LOADA(A1h_, A1l_, 8 + quad, 0) COMP(acc, 1, 1) LOADB(1, 1)   // next step pos1
        LOADA(A1h_, A1l_, 12 + quad, 1) COMP(acc, 0, 2) LOADB(2, 2)  // next step pos2
                                       COMP(acc, 1, 0) LOADB(0, 0)   // next step pos0
        BARRIER();                           // B4: all A1/A0 reads done

        // ---- cell 1 -> write h1 (A1 chunks 0..15) ----
#pragma unroll
        for (int mt = 0; mt < 2; ++mt) {
#pragma unroll
            for (int r = 0; r < 4; ++r) {
                float ig = sigm(acc[mt][0][r]);
                float fg = sigm(acc[mt][1][r]);
                float gg = tanh_fast(acc[mt][2][r]);
                float og = sigm(acc[mt][3][r]);
                float cn = fg * c1[mt][r] + ig * gg;
                c1[mt][r] = cn;
                float h = og * tanh_fast(cn);
                unsigned short hi = bf16_rn(h);
                int row = mt * 16 + quad * 4 + r;
                int i1 = ((u >> 3) * ROWP + row) * 8 + uo;
                A1h_[i1] = hi;
                A1l_[i1] = bf16_rn(h - bf16_to_f(hi));
            }
        }

        // ---- decode head ----
        if (t >= LOOKBACK) {
            BARRIER();                       // B5: h1(t) visible
            int r = tid >> 4, sub = tid & 15;
            float p = 0.0f;
#pragma unroll
            for (int i = 0; i < HIDDEN / 16; ++i) {
                int uu = sub + i * 16;
                int idx = ((uu >> 3) * ROWP + r) * 8 + (uu & 7);
                p += (bf16_to_f(A1h_[idx]) + bf16_to_f(A1l_[idx])) * wfcs[uu];
            }
#pragma unroll
            for (int off = 8; off; off >>= 1) p += __shfl_down(p, off, 16);
            if (sub == 0) {
                float pr = p + bfc;
                out[(size_t)(batch0 + r) * HORIZON + (t - LOOKBACK)] = pr;
                if (t + 1 < TTOT) {          // BG feedback -> x(t+1) slot k=0
                    unsigned short hi = bf16_rn(pr);
                    A0h[r * 8] = hi;
                    A0l[r * 8] = bf16_rn(pr - bf16_to_f(hi));
                }
            }
            BARRIER();                       // B6: bg slot visible
        }
    }
#undef WPOS
#undef LOADB
#undef LOADA
#undef COMP
}

extern "C" void kernel_launch(void* const* d_in, const int* in_sizes, int n_in,
                              void* d_out, int out_size, void* d_ws, size_t ws_size,
                              hipStream_t stream) {
    const float* input = (const float*)d_in[0];
    const float* Wih0  = (const float*)d_in[1];
    const float* Whh0  = (const float*)d_in[2];
    const float* bi0   = (const float*)d_in[3];
    const float* bh0   = (const float*)d_in[4];
    const float* Wih1  = (const float*)d_in[5];
    const float* Whh1  = (const float*)d_in[6];
    const float* bi1   = (const float*)d_in[7];
    const float* bh1   = (const float*)d_in[8];
    const float* W_fc  = (const float*)d_in[9];
    const float* b_fc  = (const float*)d_in[10];

    unsigned short* wfrag = (unsigned short*)d_ws;
    float* bias = (float*)((char*)d_ws + (size_t)W_SHORTS * sizeof(unsigned short));

    int total = W_SHORTS + 2 * GATES;
    setup_kernel<<<(total + 255) / 256, 256, 0, stream>>>(
        Wih0, Whh0, bi0, bh0, Wih1, Whh1, bi1, bh1, wfrag, bias);

    lstm_kernel<<<BATCH / TILE_B, NTHREADS, 0, stream>>>(
        input, wfrag, bias, W_fc, b_fc, (float*)d_out);
}